// Round 2
// baseline (40544.052 us; speedup 1.0000x reference)
//
#include <hip/hip_runtime.h>
#include <hip/hip_cooperative_groups.h>
#include <math.h>

namespace cg = cooperative_groups;

typedef short  s16x8 __attribute__((ext_vector_type(8)));
typedef float  f32x4 __attribute__((ext_vector_type(4)));
typedef unsigned short u16;

#define MFMA16(a, b, c) __builtin_amdgcn_mfma_f32_16x16x32_bf16((a), (b), (c), 0, 0, 0)

#define BB 128
#define SS 512
#define HH 512
#define VV 30
#define TT 64

__device__ __forceinline__ float b2f(u16 v) {
  union { unsigned int u; float f; } c; c.u = ((unsigned int)v) << 16; return c.f;
}
__device__ __forceinline__ u16 f2b(float f) {
  union { float f; unsigned int u; } c; c.f = f;
  unsigned int r = (c.u + 0x7FFFu + ((c.u >> 16) & 1u)) >> 16;
  return (u16)r;
}
__device__ __forceinline__ float sigm(float x) { return 1.f / (1.f + expf(-x)); }
__device__ __forceinline__ s16x8 ldf(const u16* p) { return *(const s16x8*)p; }

// Split-f32 format: per logical row of K=512, u16 row of 1024: [hi x512 | lo x512].
// hi = bf16(v), lo = bf16(v - hi). GEMM does hi*hi + hi*lo + lo*hi (Markidis).

// =====================================================================
// Dual-input GRU cell (layer-1 / decoder): 64 block-roles x 256 thr.
// Role bx: j0=(bx>>1)*16 H-cols, m0=(bx&1)*64; wave covers 16 m-rows.
// 6 gate tiles: 0..2 = A1@Wih rows, 3..5 = A2@Whh rows. Lane-local epilogue.
// =====================================================================
__device__ __forceinline__ void gru_dual(
    int bx,
    const u16* __restrict__ A1s, const int* __restrict__ gather,
    const u16* __restrict__ A2s,
    const u16* __restrict__ Wihs, const u16* __restrict__ Whhs,
    const float* __restrict__ bih, const float* __restrict__ bhh,
    float* __restrict__ hf, u16* __restrict__ hs_new,
    u16* __restrict__ oe, size_t oe_mstride)
{
  const int tid  = threadIdx.x;
  const int wave = tid >> 6, lane = tid & 63;
  const int lrow = lane & 15, lq = lane >> 4;
  const int j0 = (bx >> 1) * 16;
  const int m0 = (bx & 1) * 64 + wave * 16;

  const u16* a1p;
  if (gather) a1p = A1s + (size_t)gather[m0 + lrow] * 1024 + lq * 8;
  else        a1p = A1s + (size_t)(m0 + lrow) * 1024 + lq * 8;
  const u16* a2p = A2s + (size_t)(m0 + lrow) * 1024 + lq * 8;

  const u16* bp[6];
#pragma unroll
  for (int t = 0; t < 6; ++t) {
    int g = (t < 3) ? t : t - 3;
    const u16* W = (t < 3) ? Wihs : Whhs;
    bp[t] = W + (size_t)(g * HH + j0 + lrow) * 1024 + lq * 8;
  }

  f32x4 acc[6];
#pragma unroll
  for (int t = 0; t < 6; ++t) acc[t] = (f32x4){0.f, 0.f, 0.f, 0.f};

  for (int ks = 0; ks < HH; ks += 32) {
    s16x8 a1h = ldf(a1p), a1l = ldf(a1p + 512); a1p += 32;
    s16x8 a2h = ldf(a2p), a2l = ldf(a2p + 512); a2p += 32;
#pragma unroll
    for (int t = 0; t < 6; ++t) {
      s16x8 bh = ldf(bp[t]), bl = ldf(bp[t] + 512); bp[t] += 32;
      s16x8 ah = (t < 3) ? a1h : a2h;
      s16x8 al = (t < 3) ? a1l : a2l;
      acc[t] = MFMA16(ah, bh, acc[t]);
      acc[t] = MFMA16(ah, bl, acc[t]);
      acc[t] = MFMA16(al, bh, acc[t]);
    }
  }

  const int c = j0 + lrow;
  const float bir = bih[c], biz = bih[HH + c], bin = bih[2 * HH + c];
  const float bhr = bhh[c], bhz = bhh[HH + c], bhn = bhh[2 * HH + c];
#pragma unroll
  for (int r = 0; r < 4; ++r) {
    int m = m0 + lq * 4 + r;
    float ir = acc[0][r] + bir, iz = acc[1][r] + biz, inn = acc[2][r] + bin;
    float hr = acc[3][r] + bhr, hz = acc[4][r] + bhz, hn = acc[5][r] + bhn;
    float rr = sigm(ir + hr);
    float zz = sigm(iz + hz);
    float nn = tanhf(inn + rr * hn);
    float hp = hf[(size_t)m * HH + c];
    float hv = (1.f - zz) * nn + zz * hp;
    hf[(size_t)m * HH + c] = hv;
    u16 hi = f2b(hv);
    hs_new[(size_t)m * 1024 + c]       = hi;
    hs_new[(size_t)m * 1024 + 512 + c] = f2b(hv - b2f(hi));
    if (oe) oe[(size_t)m * oe_mstride + c] = hi;
  }
}

// Encoder layer-0: gh via MFMA (split A, split Whh0); gi inline f32 (K=2, exact).
// 32 block-roles x 256 thr; wave covers 32 m-rows (2 m-tiles).
__device__ __forceinline__ void gru_l0(
    int bx, int p,
    const float* __restrict__ x, const float* __restrict__ Wih0,
    const u16* __restrict__ Whh0s,
    const float* __restrict__ bih0, const float* __restrict__ bhh0,
    const u16* __restrict__ As,
    float* __restrict__ af, u16* __restrict__ as_new)
{
  const int tid  = threadIdx.x;
  const int wave = tid >> 6, lane = tid & 63;
  const int lrow = lane & 15, lq = lane >> 4;
  const int j0 = bx * 16;
  const int mw = wave * 32;

  const u16* ap0 = As + (size_t)(mw + lrow) * 1024 + lq * 8;
  const u16* ap1 = As + (size_t)(mw + 16 + lrow) * 1024 + lq * 8;
  const u16* bp[3];
#pragma unroll
  for (int t = 0; t < 3; ++t)
    bp[t] = Whh0s + (size_t)(t * HH + j0 + lrow) * 1024 + lq * 8;

  f32x4 acc[2][3];
#pragma unroll
  for (int i = 0; i < 2; ++i)
#pragma unroll
    for (int t = 0; t < 3; ++t) acc[i][t] = (f32x4){0.f, 0.f, 0.f, 0.f};

  for (int ks = 0; ks < HH; ks += 32) {
    s16x8 a0h = ldf(ap0), a0l = ldf(ap0 + 512); ap0 += 32;
    s16x8 a1h = ldf(ap1), a1l = ldf(ap1 + 512); ap1 += 32;
#pragma unroll
    for (int t = 0; t < 3; ++t) {
      s16x8 bh = ldf(bp[t]), bl = ldf(bp[t] + 512); bp[t] += 32;
      acc[0][t] = MFMA16(a0h, bh, acc[0][t]);
      acc[0][t] = MFMA16(a0h, bl, acc[0][t]);
      acc[0][t] = MFMA16(a0l, bh, acc[0][t]);
      acc[1][t] = MFMA16(a1h, bh, acc[1][t]);
      acc[1][t] = MFMA16(a1h, bl, acc[1][t]);
      acc[1][t] = MFMA16(a1l, bh, acc[1][t]);
    }
  }

  const int c = j0 + lrow;
  const float bir = bih0[c], biz = bih0[HH + c], bin = bih0[2 * HH + c];
  const float bhr = bhh0[c], bhz = bhh0[HH + c], bhn = bhh0[2 * HH + c];
  const float wr0 = Wih0[(size_t)c * 2],            wr1 = Wih0[(size_t)c * 2 + 1];
  const float wz0 = Wih0[(size_t)(HH + c) * 2],     wz1 = Wih0[(size_t)(HH + c) * 2 + 1];
  const float wn0 = Wih0[(size_t)(2 * HH + c) * 2], wn1 = Wih0[(size_t)(2 * HH + c) * 2 + 1];
#pragma unroll
  for (int tm = 0; tm < 2; ++tm) {
#pragma unroll
    for (int r = 0; r < 4; ++r) {
      int m = mw + tm * 16 + lq * 4 + r;
      float x0 = x[((size_t)m * SS + p) * 2];
      float x1 = x[((size_t)m * SS + p) * 2 + 1];
      float ir  = bir + x0 * wr0 + x1 * wr1;
      float iz  = biz + x0 * wz0 + x1 * wz1;
      float inn = bin + x0 * wn0 + x1 * wn1;
      float hr = acc[tm][0][r] + bhr, hz = acc[tm][1][r] + bhz, hn = acc[tm][2][r] + bhn;
      float rr = sigm(ir + hr);
      float zz = sigm(iz + hz);
      float nn = tanhf(inn + rr * hn);
      float hp = af[(size_t)m * HH + c];
      float hv = (1.f - zz) * nn + zz * hp;
      af[(size_t)m * HH + c] = hv;
      u16 hi = f2b(hv);
      as_new[(size_t)m * 1024 + c]       = hi;
      as_new[(size_t)m * 1024 + 512 + c] = f2b(hv - b2f(hi));
    }
  }
}

// sim[s][b] = dot(out_enc[b,s,:], n1[b,:]). 256 block-roles: b=bx>>1,
// s-half=bx&1; wave covers 64 s-rows.
__device__ __forceinline__ void sim_block(
    int bx, const float* __restrict__ n1f, const u16* __restrict__ oe,
    float* __restrict__ simt)
{
  const int b = bx >> 1, sc = bx & 1;
  const int wave = threadIdx.x >> 6, lane = threadIdx.x & 63;
  float xr[8];
  const float* xp = n1f + (size_t)b * HH + lane * 8;
#pragma unroll
  for (int j = 0; j < 8; ++j) xr[j] = xp[j];
  int s0 = sc * 256 + wave * 64;
  for (int i = 0; i < 64; ++i) {
    int s = s0 + i;
    s16x8 ov = *(const s16x8*)(oe + ((size_t)b * SS + s) * HH + lane * 8);
    float acc = 0.f;
#pragma unroll
    for (int j = 0; j < 8; ++j) acc += xr[j] * b2f((u16)ov[j]);
    for (int off = 32; off; off >>= 1) acc += __shfl_down(acc, off);
    if (lane == 0) simt[(size_t)s * BB + b] = acc;
  }
}

// Fused: softmax over BATCH (reference dim=0 quirk) -> attention -> logits ->
// argmax feedback. One block-role per batch element.
__device__ __forceinline__ void attn_block(
    int b, int tstep, const float* __restrict__ simt, const float* __restrict__ n1f,
    const u16* __restrict__ oe, const float* __restrict__ fcW,
    const float* __restrict__ fcb, float* __restrict__ dout,
    int* __restrict__ tok)
{
  __shared__ float wsm[SS];
  __shared__ float xv[2 * HH];
  __shared__ float lg[32];
  const int t = threadIdx.x;

  for (int s = t; s < SS; s += 256) {
    const float* row = simt + (size_t)s * BB;
    float mx = -1e30f;
    for (int i = 0; i < BB; ++i) mx = fmaxf(mx, row[i]);
    float e = 0.f;
    for (int i = 0; i < BB; ++i) e += expf(row[i] - mx);
    wsm[s] = expf(row[b] - mx) / e;
  }
  xv[t]       = n1f[(size_t)b * HH + t];
  xv[t + 256] = n1f[(size_t)b * HH + t + 256];
  __syncthreads();

  {
    float a0 = 0.f, a1 = 0.f;
    const u16* base = oe + (size_t)b * SS * HH;
    for (int s = 0; s < SS; ++s) {
      float w = wsm[s];
      a0 += w * b2f(base[(size_t)s * HH + t]);
      a1 += w * b2f(base[(size_t)s * HH + t + 256]);
    }
    xv[HH + t]       = a0;
    xv[HH + t + 256] = a1;
  }
  __syncthreads();

  int wave = t >> 6, lane = t & 63;
  for (int v = wave; v < VV; v += 4) {
    const float* wr = fcW + (size_t)v * (2 * HH);
    float acc = 0.f;
#pragma unroll
    for (int i = 0; i < 16; ++i) acc += xv[i * 64 + lane] * wr[i * 64 + lane];
    for (int off = 32; off; off >>= 1) acc += __shfl_down(acc, off);
    if (lane == 0) {
      float lv = acc + fcb[v];
      lg[v] = lv;
      dout[(size_t)b * (TT * VV) + (size_t)tstep * VV + v] = lv;
    }
  }
  __syncthreads();

  if (t == 0) {
    float best = lg[0]; int bi = 0;
    for (int v = 1; v < VV; ++v) if (lg[v] > best) { best = lg[v]; bi = v; }
    tok[b] = bi;
  }
}

// =====================================================================
// Persistent encoder (cooperative): 96 blocks, 513 phases, grid.sync().
// Phase p: blocks 0..31 = layer0@t=p (p<S); 32..95 = layer1@t=p-1 (p>0).
// =====================================================================
__global__ __launch_bounds__(256) void enc_persist(
    const float* __restrict__ x, const float* __restrict__ Wih0,
    const u16* __restrict__ Whh0s,
    const float* __restrict__ bih0, const float* __restrict__ bhh0,
    const u16* __restrict__ Wih1s, const u16* __restrict__ Whh1s,
    const float* __restrict__ bih1, const float* __restrict__ bhh1,
    u16* ABF0, u16* ABF1, float* af,
    u16* CBF0, u16* CBF1, float* cf,
    u16* out_enc)
{
  cg::grid_group grid = cg::this_grid();
  const int bx = blockIdx.x;
  const u16* pa = ABF0; u16* pa_n = ABF1;
  const u16* pc = CBF0; u16* pc_n = CBF1;
  for (int p = 0; p <= SS; ++p) {
    if (bx < 32) {
      if (p < SS) gru_l0(bx, p, x, Wih0, Whh0s, bih0, bhh0, pa, af, pa_n);
    } else {
      if (p > 0) {
        u16* oe = out_enc + (size_t)(p - 1) * HH;
        gru_dual(bx - 32, pa, nullptr, pc, Wih1s, Whh1s, bih1, bhh1,
                 cf, pc_n, oe, (size_t)SS * HH);
      }
    }
    grid.sync();
    const u16* tp;
    tp = pa; pa = pa_n; pa_n = (u16*)tp;
    tp = pc; pc = pc_n; pc_n = (u16*)tp;
  }
}

// =====================================================================
// Persistent decoder (cooperative): 256 blocks, 64 steps x 4 grid.sync().
// =====================================================================
__global__ __launch_bounds__(256) void dec_persist(
    const u16* __restrict__ EMBs, int* tok,
    const u16* __restrict__ WdIH0, const u16* __restrict__ WdHH0,
    const float* __restrict__ dbih0, const float* __restrict__ dbhh0,
    const u16* __restrict__ WdIH1, const u16* __restrict__ WdHH1,
    const float* __restrict__ dbih1, const float* __restrict__ dbhh1,
    float* af, float* cf,
    u16* D0A, u16* D0B, u16* D1A, u16* D1B,
    const u16* __restrict__ oe, float* simt,
    const float* __restrict__ fcW, const float* __restrict__ fcb,
    float* dout)
{
  cg::grid_group grid = cg::this_grid();
  const int bx = blockIdx.x;
  const u16* d0c = D0A; u16* d0n = D0B;
  const u16* d1c = D1A; u16* d1n = D1B;
  for (int t = 0; t < TT; ++t) {
    if (bx < 64)
      gru_dual(bx, EMBs, tok, d0c, WdIH0, WdHH0, dbih0, dbhh0, af, d0n,
               nullptr, 0);
    grid.sync();
    { const u16* tp = d0c; d0c = d0n; d0n = (u16*)tp; }

    if (bx < 64)
      gru_dual(bx, d0c, nullptr, d1c, WdIH1, WdHH1, dbih1, dbhh1, cf, d1n,
               nullptr, 0);
    grid.sync();
    { const u16* tp = d1c; d1c = d1n; d1n = (u16*)tp; }

    sim_block(bx, cf, oe, simt);
    grid.sync();

    if (bx < BB) attn_block(bx, t, simt, cf, oe, fcW, fcb, dout, tok);
    grid.sync();
  }
}

// =====================================================================
// Fallback per-phase kernels (used only if cooperative launch fails).
// =====================================================================
__global__ __launch_bounds__(256) void enc_phase(
    int p,
    const float* __restrict__ x, const float* __restrict__ Wih0,
    const u16* __restrict__ Whh0s,
    const float* __restrict__ bih0, const float* __restrict__ bhh0,
    const u16* __restrict__ Wih1s, const u16* __restrict__ Whh1s,
    const float* __restrict__ bih1, const float* __restrict__ bhh1,
    const u16* abf_cur, u16* abf_new, float* af,
    const u16* cbf_cur, u16* cbf_new, float* cf,
    u16* out_enc)
{
  int bx = blockIdx.x;
  if (bx < 32) {
    if (p >= SS) return;
    gru_l0(bx, p, x, Wih0, Whh0s, bih0, bhh0, abf_cur, af, abf_new);
  } else {
    if (p == 0) return;
    u16* oe = out_enc + (size_t)(p - 1) * HH;
    gru_dual(bx - 32, abf_cur, nullptr, cbf_cur, Wih1s, Whh1s, bih1, bhh1,
             cf, cbf_new, oe, (size_t)SS * HH);
  }
}

__global__ __launch_bounds__(256) void dec_gru(
    const u16* A1s, const int* gather, const u16* A2s,
    const u16* __restrict__ Wihs, const u16* __restrict__ Whhs,
    const float* __restrict__ bih, const float* __restrict__ bhh,
    float* hf, u16* hs_new)
{
  gru_dual(blockIdx.x, A1s, gather, A2s, Wihs, Whhs, bih, bhh, hf, hs_new,
           nullptr, 0);
}

__global__ __launch_bounds__(256) void sim_kernel(
    const float* __restrict__ n1f, const u16* __restrict__ oe,
    float* __restrict__ simt)
{
  sim_block(blockIdx.x, n1f, oe, simt);
}

__global__ __launch_bounds__(256) void attn_kernel(
    int tstep, const float* __restrict__ simt, const float* __restrict__ n1f,
    const u16* __restrict__ oe, const float* __restrict__ fcW,
    const float* __restrict__ fcb, float* __restrict__ dout,
    int* __restrict__ tok)
{
  attn_block(blockIdx.x, tstep, simt, n1f, oe, fcW, fcb, dout, tok);
}

// Split all 7 weight matrices + embedding in one launch.
__global__ __launch_bounds__(256) void splitall(
    const float* __restrict__ s0, u16* d0, const float* __restrict__ s1, u16* d1,
    const float* __restrict__ s2, u16* d2, const float* __restrict__ s3, u16* d3,
    const float* __restrict__ s4, u16* d4, const float* __restrict__ s5, u16* d5,
    const float* __restrict__ s6, u16* d6, const float* __restrict__ s7, u16* d7)
{
  const int WN = 3 * HH * HH;  // 786432
  int i = blockIdx.x * 256 + threadIdx.x;
  const float* s; u16* d; int j;
  if      (i < 1 * WN) { s = s0; d = d0; j = i; }
  else if (i < 2 * WN) { s = s1; d = d1; j = i - 1 * WN; }
  else if (i < 3 * WN) { s = s2; d = d2; j = i - 2 * WN; }
  else if (i < 4 * WN) { s = s3; d = d3; j = i - 3 * WN; }
  else if (i < 5 * WN) { s = s4; d = d4; j = i - 4 * WN; }
  else if (i < 6 * WN) { s = s5; d = d5; j = i - 5 * WN; }
  else if (i < 7 * WN) { s = s6; d = d6; j = i - 6 * WN; }
  else { j = i - 7 * WN; if (j >= VV * HH) return; s = s7; d = d7; }
  int r = j >> 9, k = j & 511;
  float v = s[j];
  u16 hi = f2b(v);
  d[(size_t)r * 1024 + k]       = hi;
  d[(size_t)r * 1024 + 512 + k] = f2b(v - b2f(hi));
}

__global__ __launch_bounds__(256) void initk(
    float* af, float* cf, u16* b0, u16* b1, u16* b2, u16* b3, int* tok)
{
  int i = blockIdx.x * 256 + threadIdx.x;   // 131072 threads
  b0[i] = 0; b1[i] = 0; b2[i] = 0; b3[i] = 0;
  if (i < BB * HH) { af[i] = 0.f; cf[i] = 0.f; }
  if (i < BB) tok[i] = 0;
}

__global__ __launch_bounds__(256) void finalize(
    const float* __restrict__ d0, const float* __restrict__ d1,
    float* __restrict__ oh)
{
  int i = blockIdx.x * 256 + threadIdx.x;
  oh[i]           = d0[i];
  oh[BB * HH + i] = d1[i];
}

extern "C" void kernel_launch(void* const* d_in, const int* in_sizes, int n_in,
                              void* d_out, int out_size, void* d_ws, size_t ws_size,
                              hipStream_t stream) {
  const float* x     = (const float*)d_in[0];
  const float* emb   = (const float*)d_in[1];
  const float* eWih0 = (const float*)d_in[2];
  const float* eWhh0 = (const float*)d_in[3];
  const float* ebih0 = (const float*)d_in[4];
  const float* ebhh0 = (const float*)d_in[5];
  const float* eWih1 = (const float*)d_in[6];
  const float* eWhh1 = (const float*)d_in[7];
  const float* ebih1 = (const float*)d_in[8];
  const float* ebhh1 = (const float*)d_in[9];
  const float* dWih0 = (const float*)d_in[10];
  const float* dWhh0 = (const float*)d_in[11];
  const float* dbih0 = (const float*)d_in[12];
  const float* dbhh0 = (const float*)d_in[13];
  const float* dWih1 = (const float*)d_in[14];
  const float* dWhh1 = (const float*)d_in[15];
  const float* dbih1 = (const float*)d_in[16];
  const float* dbhh1 = (const float*)d_in[17];
  const float* fcW   = (const float*)d_in[18];
  const float* fcb   = (const float*)d_in[19];
  float* dout = (float*)d_out;

  char* wsb = (char*)d_ws;
  float* af   = (float*)(wsb + 0);          // 128x512 f32 (a / d0 state, RMW)
  float* cf   = (float*)(wsb + 262144);     // 128x512 f32 (c / d1 state, RMW)
  u16* ABF0   = (u16*)(wsb + 524288);       // split states 128x1024 u16 each
  u16* ABF1   = (u16*)(wsb + 786432);
  u16* CBF0   = (u16*)(wsb + 1048576);
  u16* CBF1   = (u16*)(wsb + 1310720);
  int* tok    = (int*)(wsb + 1572864);
  float* simt = (float*)(wsb + 1573376);    // [S][B] f32, 256 KB
  u16* WeHH0  = (u16*)(wsb + 1835520);      // split weights, 3 MB each
  u16* WeIH1  = (u16*)(wsb + 4981248);
  u16* WeHH1  = (u16*)(wsb + 8126976);
  u16* WdIH0  = (u16*)(wsb + 11272704);
  u16* WdHH0  = (u16*)(wsb + 14418432);
  u16* WdIH1  = (u16*)(wsb + 17564160);
  u16* WdHH1  = (u16*)(wsb + 20709888);
  u16* EMBs   = (u16*)(wsb + 23855616);     // 30x1024 u16
  u16* oe     = (u16*)(wsb + 23917056);     // out_enc bf16 [B][S][H], 64 MiB

  initk<<<512, 256, 0, stream>>>(af, cf, ABF0, ABF1, CBF0, CBF1, tok);

  splitall<<<21564, 256, 0, stream>>>(eWhh0, WeHH0, eWih1, WeIH1, eWhh1, WeHH1,
                                      dWih0, WdIH0, dWhh0, WdHH0, dWih1, WdIH1,
                                      dWhh1, WdHH1, emb, EMBs);

  // ---- encoder: cooperative persistent kernel, fallback = per-phase ----
  {
    void* ea[] = {
      (void*)&x, (void*)&eWih0, (void*)&WeHH0, (void*)&ebih0, (void*)&ebhh0,
      (void*)&WeIH1, (void*)&WeHH1, (void*)&ebih1, (void*)&ebhh1,
      (void*)&ABF0, (void*)&ABF1, (void*)&af,
      (void*)&CBF0, (void*)&CBF1, (void*)&cf, (void*)&oe
    };
    hipError_t e = hipLaunchCooperativeKernel((void*)enc_persist, dim3(96),
                                              dim3(256), ea, 0, stream);
    if (e != hipSuccess) {
      const u16* pa = ABF0; u16* pa_n = ABF1;
      const u16* pc = CBF0; u16* pc_n = CBF1;
      for (int p = 0; p <= SS; ++p) {
        enc_phase<<<96, 256, 0, stream>>>(p, x, eWih0, WeHH0, ebih0, ebhh0,
                                          WeIH1, WeHH1, ebih1, ebhh1,
                                          pa, pa_n, af, pc, pc_n, cf, oe);
        const u16* tp;
        tp = pa; pa = pa_n; pa_n = (u16*)tp;
        tp = pc; pc = pc_n; pc_n = (u16*)tp;
      }
    }
  }

  // a_511 split in ABF0 (written p=511); c_511 split in CBF1 (written p=512)
  {
    u16* D0A = ABF0; u16* D0B = ABF1; u16* D1A = CBF1; u16* D1B = CBF0;
    void* da[] = {
      (void*)&EMBs, (void*)&tok,
      (void*)&WdIH0, (void*)&WdHH0, (void*)&dbih0, (void*)&dbhh0,
      (void*)&WdIH1, (void*)&WdHH1, (void*)&dbih1, (void*)&dbhh1,
      (void*)&af, (void*)&cf,
      (void*)&D0A, (void*)&D0B, (void*)&D1A, (void*)&D1B,
      (void*)&oe, (void*)&simt, (void*)&fcW, (void*)&fcb, (void*)&dout
    };
    hipError_t e = hipLaunchCooperativeKernel((void*)dec_persist, dim3(256),
                                              dim3(256), da, 0, stream);
    if (e != hipSuccess) {
      const u16* d0c = D0A; u16* d0n = D0B;
      const u16* d1c = D1A; u16* d1n = D1B;
      for (int t = 0; t < TT; ++t) {
        dec_gru<<<64, 256, 0, stream>>>(EMBs, tok, d0c, WdIH0, WdHH0,
                                        dbih0, dbhh0, af, d0n);
        const u16* tp = d0c; d0c = d0n; d0n = (u16*)tp;
        dec_gru<<<64, 256, 0, stream>>>(d0c, nullptr, d1c, WdIH1, WdHH1,
                                        dbih1, dbhh1, cf, d1n);
        tp = d1c; d1c = d1n; d1n = (u16*)tp;
        sim_kernel<<<256, 256, 0, stream>>>(cf, oe, simt);
        attn_kernel<<<128, 256, 0, stream>>>(t, simt, cf, oe, fcW, fcb, dout, tok);
      }
    }
  }

  finalize<<<256, 256, 0, stream>>>(af, cf, dout + (size_t)BB * TT * VV);
}

// Round 3
// 32696.457 us; speedup vs baseline: 1.2400x; 1.2400x over previous
//
#include <hip/hip_runtime.h>
#include <math.h>

typedef short  s16x8 __attribute__((ext_vector_type(8)));
typedef float  f32x4 __attribute__((ext_vector_type(4)));
typedef unsigned short u16;

#define MFMA16(a, b, c) __builtin_amdgcn_mfma_f32_16x16x32_bf16((a), (b), (c), 0, 0, 0)

#define BB 128
#define SS 512
#define HH 512
#define VV 30
#define TT 64

__device__ __forceinline__ float b2f(u16 v) {
  union { unsigned int u; float f; } c; c.u = ((unsigned int)v) << 16; return c.f;
}
__device__ __forceinline__ u16 f2b(float f) {
  union { float f; unsigned int u; } c; c.f = f;
  unsigned int r = (c.u + 0x7FFFu + ((c.u >> 16) & 1u)) >> 16;
  return (u16)r;
}
__device__ __forceinline__ float sigm(float x) { return 1.f / (1.f + expf(-x)); }
__device__ __forceinline__ s16x8 ldf(const u16* p) { return *(const s16x8*)p; }

// ---------------------------------------------------------------------
// Lightweight grid barrier, agent scope (NOT system scope — keeps the
// MALL/L3 working set resident, unlike cg::grid_group::sync()).
// Monotone counter in __device__ global (no workspace-bounds risk).
// target = nblocks * (1-based barrier index). Release add publishes this
// XCD's L2 to MALL; acquire load invalidates stale L1/L2 lines.
// Timeout (~5ms @100MHz realtime clock) converts any pathological hang
// into a terminating (wrong-answer) run instead of a dead container.
// ---------------------------------------------------------------------
__device__ unsigned int g_bar[2];

__device__ __forceinline__ void gridbar(unsigned int* cnt, unsigned int target) {
  __syncthreads();
  if (threadIdx.x == 0) {
    __hip_atomic_fetch_add(cnt, 1u, __ATOMIC_RELEASE, __HIP_MEMORY_SCOPE_AGENT);
    unsigned long long t0 = __builtin_amdgcn_s_memrealtime();
    while (__hip_atomic_load(cnt, __ATOMIC_RELAXED, __HIP_MEMORY_SCOPE_AGENT) < target) {
      __builtin_amdgcn_s_sleep(2);
      if (__builtin_amdgcn_s_memrealtime() - t0 > (1ull << 19)) break;
    }
    (void)__hip_atomic_load(cnt, __ATOMIC_ACQUIRE, __HIP_MEMORY_SCOPE_AGENT);
  }
  __syncthreads();
}

// Split-f32 format: per logical row of K=512, u16 row of 1024: [hi x512 | lo x512].
// hi = bf16(v), lo = bf16(v - hi). GEMM does hi*hi + hi*lo + lo*hi (Markidis).

// =====================================================================
// Dual-input GRU cell (layer-1 / decoder): 64 block-roles x 256 thr.
// Role bx: j0=(bx>>1)*16 H-cols, m0=(bx&1)*64; wave covers 16 m-rows.
// 6 gate tiles: 0..2 = A1@Wih rows, 3..5 = A2@Whh rows. Lane-local epilogue.
// =====================================================================
__device__ __forceinline__ void gru_dual(
    int bx,
    const u16* __restrict__ A1s, const int* __restrict__ gather,
    const u16* __restrict__ A2s,
    const u16* __restrict__ Wihs, const u16* __restrict__ Whhs,
    const float* __restrict__ bih, const float* __restrict__ bhh,
    float* __restrict__ hf, u16* __restrict__ hs_new,
    u16* __restrict__ oe, size_t oe_mstride)
{
  const int tid  = threadIdx.x;
  const int wave = tid >> 6, lane = tid & 63;
  const int lrow = lane & 15, lq = lane >> 4;
  const int j0 = (bx >> 1) * 16;
  const int m0 = (bx & 1) * 64 + wave * 16;

  const u16* a1p;
  if (gather) a1p = A1s + (size_t)gather[m0 + lrow] * 1024 + lq * 8;
  else        a1p = A1s + (size_t)(m0 + lrow) * 1024 + lq * 8;
  const u16* a2p = A2s + (size_t)(m0 + lrow) * 1024 + lq * 8;

  const u16* bp[6];
#pragma unroll
  for (int t = 0; t < 6; ++t) {
    int g = (t < 3) ? t : t - 3;
    const u16* W = (t < 3) ? Wihs : Whhs;
    bp[t] = W + (size_t)(g * HH + j0 + lrow) * 1024 + lq * 8;
  }

  f32x4 acc[6];
#pragma unroll
  for (int t = 0; t < 6; ++t) acc[t] = (f32x4){0.f, 0.f, 0.f, 0.f};

  for (int ks = 0; ks < HH; ks += 32) {
    s16x8 a1h = ldf(a1p), a1l = ldf(a1p + 512); a1p += 32;
    s16x8 a2h = ldf(a2p), a2l = ldf(a2p + 512); a2p += 32;
#pragma unroll
    for (int t = 0; t < 6; ++t) {
      s16x8 bh = ldf(bp[t]), bl = ldf(bp[t] + 512); bp[t] += 32;
      s16x8 ah = (t < 3) ? a1h : a2h;
      s16x8 al = (t < 3) ? a1l : a2l;
      acc[t] = MFMA16(ah, bh, acc[t]);
      acc[t] = MFMA16(ah, bl, acc[t]);
      acc[t] = MFMA16(al, bh, acc[t]);
    }
  }

  const int c = j0 + lrow;
  const float bir = bih[c], biz = bih[HH + c], bin = bih[2 * HH + c];
  const float bhr = bhh[c], bhz = bhh[HH + c], bhn = bhh[2 * HH + c];
#pragma unroll
  for (int r = 0; r < 4; ++r) {
    int m = m0 + lq * 4 + r;
    float ir = acc[0][r] + bir, iz = acc[1][r] + biz, inn = acc[2][r] + bin;
    float hr = acc[3][r] + bhr, hz = acc[4][r] + bhz, hn = acc[5][r] + bhn;
    float rr = sigm(ir + hr);
    float zz = sigm(iz + hz);
    float nn = tanhf(inn + rr * hn);
    float hp = hf[(size_t)m * HH + c];
    float hv = (1.f - zz) * nn + zz * hp;
    hf[(size_t)m * HH + c] = hv;
    u16 hi = f2b(hv);
    hs_new[(size_t)m * 1024 + c]       = hi;
    hs_new[(size_t)m * 1024 + 512 + c] = f2b(hv - b2f(hi));
    if (oe) oe[(size_t)m * oe_mstride + c] = hi;
  }
}

// Encoder layer-0: gh via MFMA (split A, split Whh0); gi inline f32 (K=2, exact).
// 32 block-roles x 256 thr; wave covers 32 m-rows (2 m-tiles).
__device__ __forceinline__ void gru_l0(
    int bx, int p,
    const float* __restrict__ x, const float* __restrict__ Wih0,
    const u16* __restrict__ Whh0s,
    const float* __restrict__ bih0, const float* __restrict__ bhh0,
    const u16* __restrict__ As,
    float* __restrict__ af, u16* __restrict__ as_new)
{
  const int tid  = threadIdx.x;
  const int wave = tid >> 6, lane = tid & 63;
  const int lrow = lane & 15, lq = lane >> 4;
  const int j0 = bx * 16;
  const int mw = wave * 32;

  const u16* ap0 = As + (size_t)(mw + lrow) * 1024 + lq * 8;
  const u16* ap1 = As + (size_t)(mw + 16 + lrow) * 1024 + lq * 8;
  const u16* bp[3];
#pragma unroll
  for (int t = 0; t < 3; ++t)
    bp[t] = Whh0s + (size_t)(t * HH + j0 + lrow) * 1024 + lq * 8;

  f32x4 acc[2][3];
#pragma unroll
  for (int i = 0; i < 2; ++i)
#pragma unroll
    for (int t = 0; t < 3; ++t) acc[i][t] = (f32x4){0.f, 0.f, 0.f, 0.f};

  for (int ks = 0; ks < HH; ks += 32) {
    s16x8 a0h = ldf(ap0), a0l = ldf(ap0 + 512); ap0 += 32;
    s16x8 a1h = ldf(ap1), a1l = ldf(ap1 + 512); ap1 += 32;
#pragma unroll
    for (int t = 0; t < 3; ++t) {
      s16x8 bh = ldf(bp[t]), bl = ldf(bp[t] + 512); bp[t] += 32;
      acc[0][t] = MFMA16(a0h, bh, acc[0][t]);
      acc[0][t] = MFMA16(a0h, bl, acc[0][t]);
      acc[0][t] = MFMA16(a0l, bh, acc[0][t]);
      acc[1][t] = MFMA16(a1h, bh, acc[1][t]);
      acc[1][t] = MFMA16(a1h, bl, acc[1][t]);
      acc[1][t] = MFMA16(a1l, bh, acc[1][t]);
    }
  }

  const int c = j0 + lrow;
  const float bir = bih0[c], biz = bih0[HH + c], bin = bih0[2 * HH + c];
  const float bhr = bhh0[c], bhz = bhh0[HH + c], bhn = bhh0[2 * HH + c];
  const float wr0 = Wih0[(size_t)c * 2],            wr1 = Wih0[(size_t)c * 2 + 1];
  const float wz0 = Wih0[(size_t)(HH + c) * 2],     wz1 = Wih0[(size_t)(HH + c) * 2 + 1];
  const float wn0 = Wih0[(size_t)(2 * HH + c) * 2], wn1 = Wih0[(size_t)(2 * HH + c) * 2 + 1];
#pragma unroll
  for (int tm = 0; tm < 2; ++tm) {
#pragma unroll
    for (int r = 0; r < 4; ++r) {
      int m = mw + tm * 16 + lq * 4 + r;
      float x0 = x[((size_t)m * SS + p) * 2];
      float x1 = x[((size_t)m * SS + p) * 2 + 1];
      float ir  = bir + x0 * wr0 + x1 * wr1;
      float iz  = biz + x0 * wz0 + x1 * wz1;
      float inn = bin + x0 * wn0 + x1 * wn1;
      float hr = acc[tm][0][r] + bhr, hz = acc[tm][1][r] + bhz, hn = acc[tm][2][r] + bhn;
      float rr = sigm(ir + hr);
      float zz = sigm(iz + hz);
      float nn = tanhf(inn + rr * hn);
      float hp = af[(size_t)m * HH + c];
      float hv = (1.f - zz) * nn + zz * hp;
      af[(size_t)m * HH + c] = hv;
      u16 hi = f2b(hv);
      as_new[(size_t)m * 1024 + c]       = hi;
      as_new[(size_t)m * 1024 + 512 + c] = f2b(hv - b2f(hi));
    }
  }
}

// sim[s][b] = dot(out_enc[b,s,:], n1[b,:]). 256 block-roles: b=bx>>1,
// s-half=bx&1; wave covers 64 s-rows.
__device__ __forceinline__ void sim_block(
    int bx, const float* __restrict__ n1f, const u16* __restrict__ oe,
    float* __restrict__ simt)
{
  const int b = bx >> 1, sc = bx & 1;
  const int wave = threadIdx.x >> 6, lane = threadIdx.x & 63;
  float xr[8];
  const float* xp = n1f + (size_t)b * HH + lane * 8;
#pragma unroll
  for (int j = 0; j < 8; ++j) xr[j] = xp[j];
  int s0 = sc * 256 + wave * 64;
  for (int i = 0; i < 64; ++i) {
    int s = s0 + i;
    s16x8 ov = *(const s16x8*)(oe + ((size_t)b * SS + s) * HH + lane * 8);
    float acc = 0.f;
#pragma unroll
    for (int j = 0; j < 8; ++j) acc += xr[j] * b2f((u16)ov[j]);
    for (int off = 32; off; off >>= 1) acc += __shfl_down(acc, off);
    if (lane == 0) simt[(size_t)s * BB + b] = acc;
  }
}

// Fused: softmax over BATCH (reference dim=0 quirk) -> attention -> logits ->
// argmax feedback. One block-role per batch element.
__device__ __forceinline__ void attn_block(
    int b, int tstep, const float* __restrict__ simt, const float* __restrict__ n1f,
    const u16* __restrict__ oe, const float* __restrict__ fcW,
    const float* __restrict__ fcb, float* __restrict__ dout,
    int* __restrict__ tok)
{
  __shared__ float wsm[SS];
  __shared__ float xv[2 * HH];
  __shared__ float lg[32];
  const int t = threadIdx.x;

  for (int s = t; s < SS; s += 256) {
    const float* row = simt + (size_t)s * BB;
    float mx = -1e30f;
    for (int i = 0; i < BB; ++i) mx = fmaxf(mx, row[i]);
    float e = 0.f;
    for (int i = 0; i < BB; ++i) e += expf(row[i] - mx);
    wsm[s] = expf(row[b] - mx) / e;
  }
  xv[t]       = n1f[(size_t)b * HH + t];
  xv[t + 256] = n1f[(size_t)b * HH + t + 256];
  __syncthreads();

  {
    float a0 = 0.f, a1 = 0.f;
    const u16* base = oe + (size_t)b * SS * HH;
    for (int s = 0; s < SS; ++s) {
      float w = wsm[s];
      a0 += w * b2f(base[(size_t)s * HH + t]);
      a1 += w * b2f(base[(size_t)s * HH + t + 256]);
    }
    xv[HH + t]       = a0;
    xv[HH + t + 256] = a1;
  }
  __syncthreads();

  int wave = t >> 6, lane = t & 63;
  for (int v = wave; v < VV; v += 4) {
    const float* wr = fcW + (size_t)v * (2 * HH);
    float acc = 0.f;
#pragma unroll
    for (int i = 0; i < 16; ++i) acc += xv[i * 64 + lane] * wr[i * 64 + lane];
    for (int off = 32; off; off >>= 1) acc += __shfl_down(acc, off);
    if (lane == 0) {
      float lv = acc + fcb[v];
      lg[v] = lv;
      dout[(size_t)b * (TT * VV) + (size_t)tstep * VV + v] = lv;
    }
  }
  __syncthreads();

  if (t == 0) {
    float best = lg[0]; int bi = 0;
    for (int v = 1; v < VV; ++v) if (lg[v] > best) { best = lg[v]; bi = v; }
    tok[b] = bi;
  }
}

// =====================================================================
// Persistent encoder: 96 blocks (<=256 CUs -> co-resident), 513 phases.
// Phase p: blocks 0..31 = layer0@t=p (p<S); 32..95 = layer1@t=p-1 (p>0).
// =====================================================================
__global__ __launch_bounds__(256) void enc_persist(
    const float* __restrict__ x, const float* __restrict__ Wih0,
    const u16* __restrict__ Whh0s,
    const float* __restrict__ bih0, const float* __restrict__ bhh0,
    const u16* __restrict__ Wih1s, const u16* __restrict__ Whh1s,
    const float* __restrict__ bih1, const float* __restrict__ bhh1,
    u16* ABF0, u16* ABF1, float* af,
    u16* CBF0, u16* CBF1, float* cf,
    u16* out_enc)
{
  const int bx = blockIdx.x;
  const u16* pa = ABF0; u16* pa_n = ABF1;
  const u16* pc = CBF0; u16* pc_n = CBF1;
  for (int p = 0; p <= SS; ++p) {
    if (bx < 32) {
      if (p < SS) gru_l0(bx, p, x, Wih0, Whh0s, bih0, bhh0, pa, af, pa_n);
    } else {
      if (p > 0) {
        u16* oe = out_enc + (size_t)(p - 1) * HH;
        gru_dual(bx - 32, pa, nullptr, pc, Wih1s, Whh1s, bih1, bhh1,
                 cf, pc_n, oe, (size_t)SS * HH);
      }
    }
    gridbar(&g_bar[0], 96u * (unsigned)(p + 1));
    const u16* tp;
    tp = pa; pa = pa_n; pa_n = (u16*)tp;
    tp = pc; pc = pc_n; pc_n = (u16*)tp;
  }
}

// =====================================================================
// Persistent decoder: 256 blocks (1/CU -> co-resident), 64 steps x 4 bars.
// =====================================================================
__global__ __launch_bounds__(256) void dec_persist(
    const u16* __restrict__ EMBs, int* tok,
    const u16* __restrict__ WdIH0, const u16* __restrict__ WdHH0,
    const float* __restrict__ dbih0, const float* __restrict__ dbhh0,
    const u16* __restrict__ WdIH1, const u16* __restrict__ WdHH1,
    const float* __restrict__ dbih1, const float* __restrict__ dbhh1,
    float* af, float* cf,
    u16* D0A, u16* D0B, u16* D1A, u16* D1B,
    const u16* __restrict__ oe, float* simt,
    const float* __restrict__ fcW, const float* __restrict__ fcb,
    float* dout)
{
  const int bx = blockIdx.x;
  const u16* d0c = D0A; u16* d0n = D0B;
  const u16* d1c = D1A; u16* d1n = D1B;
  unsigned int nb = 0;
  for (int t = 0; t < TT; ++t) {
    if (bx < 64)
      gru_dual(bx, EMBs, tok, d0c, WdIH0, WdHH0, dbih0, dbhh0, af, d0n,
               nullptr, 0);
    gridbar(&g_bar[1], 256u * (++nb));
    { const u16* tp = d0c; d0c = d0n; d0n = (u16*)tp; }

    if (bx < 64)
      gru_dual(bx, d0c, nullptr, d1c, WdIH1, WdHH1, dbih1, dbhh1, cf, d1n,
               nullptr, 0);
    gridbar(&g_bar[1], 256u * (++nb));
    { const u16* tp = d1c; d1c = d1n; d1n = (u16*)tp; }

    sim_block(bx, cf, oe, simt);
    gridbar(&g_bar[1], 256u * (++nb));

    if (bx < BB) attn_block(bx, t, simt, cf, oe, fcW, fcb, dout, tok);
    gridbar(&g_bar[1], 256u * (++nb));
  }
}

// Split all 7 weight matrices + embedding in one launch.
__global__ __launch_bounds__(256) void splitall(
    const float* __restrict__ s0, u16* d0, const float* __restrict__ s1, u16* d1,
    const float* __restrict__ s2, u16* d2, const float* __restrict__ s3, u16* d3,
    const float* __restrict__ s4, u16* d4, const float* __restrict__ s5, u16* d5,
    const float* __restrict__ s6, u16* d6, const float* __restrict__ s7, u16* d7)
{
  const int WN = 3 * HH * HH;  // 786432
  int i = blockIdx.x * 256 + threadIdx.x;
  const float* s; u16* d; int j;
  if      (i < 1 * WN) { s = s0; d = d0; j = i; }
  else if (i < 2 * WN) { s = s1; d = d1; j = i - 1 * WN; }
  else if (i < 3 * WN) { s = s2; d = d2; j = i - 2 * WN; }
  else if (i < 4 * WN) { s = s3; d = d3; j = i - 3 * WN; }
  else if (i < 5 * WN) { s = s4; d = d4; j = i - 4 * WN; }
  else if (i < 6 * WN) { s = s5; d = d5; j = i - 5 * WN; }
  else if (i < 7 * WN) { s = s6; d = d6; j = i - 6 * WN; }
  else { j = i - 7 * WN; if (j >= VV * HH) return; s = s7; d = d7; }
  int r = j >> 9, k = j & 511;
  float v = s[j];
  u16 hi = f2b(v);
  d[(size_t)r * 1024 + k]       = hi;
  d[(size_t)r * 1024 + 512 + k] = f2b(v - b2f(hi));
}

__global__ __launch_bounds__(256) void initk(
    float* af, float* cf, u16* b0, u16* b1, u16* b2, u16* b3, int* tok)
{
  int i = blockIdx.x * 256 + threadIdx.x;   // 131072 threads
  b0[i] = 0; b1[i] = 0; b2[i] = 0; b3[i] = 0;
  if (i < BB * HH) { af[i] = 0.f; cf[i] = 0.f; }
  if (i < BB) tok[i] = 0;
  if (i < 2) g_bar[i] = 0;
}

__global__ __launch_bounds__(256) void finalize(
    const float* __restrict__ d0, const float* __restrict__ d1,
    float* __restrict__ oh)
{
  int i = blockIdx.x * 256 + threadIdx.x;
  oh[i]           = d0[i];
  oh[BB * HH + i] = d1[i];
}

extern "C" void kernel_launch(void* const* d_in, const int* in_sizes, int n_in,
                              void* d_out, int out_size, void* d_ws, size_t ws_size,
                              hipStream_t stream) {
  const float* x     = (const float*)d_in[0];
  const float* emb   = (const float*)d_in[1];
  const float* eWih0 = (const float*)d_in[2];
  const float* eWhh0 = (const float*)d_in[3];
  const float* ebih0 = (const float*)d_in[4];
  const float* ebhh0 = (const float*)d_in[5];
  const float* eWih1 = (const float*)d_in[6];
  const float* eWhh1 = (const float*)d_in[7];
  const float* ebih1 = (const float*)d_in[8];
  const float* ebhh1 = (const float*)d_in[9];
  const float* dWih0 = (const float*)d_in[10];
  const float* dWhh0 = (const float*)d_in[11];
  const float* dbih0 = (const float*)d_in[12];
  const float* dbhh0 = (const float*)d_in[13];
  const float* dWih1 = (const float*)d_in[14];
  const float* dWhh1 = (const float*)d_in[15];
  const float* dbih1 = (const float*)d_in[16];
  const float* dbhh1 = (const float*)d_in[17];
  const float* fcW   = (const float*)d_in[18];
  const float* fcb   = (const float*)d_in[19];
  float* dout = (float*)d_out;

  char* wsb = (char*)d_ws;
  float* af   = (float*)(wsb + 0);          // 128x512 f32 (a / d0 state, RMW)
  float* cf   = (float*)(wsb + 262144);     // 128x512 f32 (c / d1 state, RMW)
  u16* ABF0   = (u16*)(wsb + 524288);       // split states 128x1024 u16 each
  u16* ABF1   = (u16*)(wsb + 786432);
  u16* CBF0   = (u16*)(wsb + 1048576);
  u16* CBF1   = (u16*)(wsb + 1310720);
  int* tok    = (int*)(wsb + 1572864);
  float* simt = (float*)(wsb + 1573376);    // [S][B] f32, 256 KB
  u16* WeHH0  = (u16*)(wsb + 1835520);      // split weights, 3 MB each
  u16* WeIH1  = (u16*)(wsb + 4981248);
  u16* WeHH1  = (u16*)(wsb + 8126976);
  u16* WdIH0  = (u16*)(wsb + 11272704);
  u16* WdHH0  = (u16*)(wsb + 14418432);
  u16* WdIH1  = (u16*)(wsb + 17564160);
  u16* WdHH1  = (u16*)(wsb + 20709888);
  u16* EMBs   = (u16*)(wsb + 23855616);     // 30x1024 u16
  u16* oe     = (u16*)(wsb + 23917056);     // out_enc bf16 [B][S][H], 64 MiB

  initk<<<512, 256, 0, stream>>>(af, cf, ABF0, ABF1, CBF0, CBF1, tok);

  splitall<<<21564, 256, 0, stream>>>(eWhh0, WeHH0, eWih1, WeIH1, eWhh1, WeHH1,
                                      dWih0, WdIH0, dWhh0, WdHH0, dWih1, WdIH1,
                                      dWhh1, WdHH1, emb, EMBs);

  enc_persist<<<96, 256, 0, stream>>>(x, eWih0, WeHH0, ebih0, ebhh0,
                                      WeIH1, WeHH1, ebih1, ebhh1,
                                      ABF0, ABF1, af, CBF0, CBF1, cf, oe);

  // a_511 split in ABF0 (written p=511); c_511 split in CBF1 (written p=512)
  dec_persist<<<256, 256, 0, stream>>>(EMBs, tok, WdIH0, WdHH0, dbih0, dbhh0,
                                       WdIH1, WdHH1, dbih1, dbhh1,
                                       af, cf, ABF0, ABF1, CBF1, CBF0,
                                       oe, simt, fcW, fcb, dout);

  finalize<<<256, 256, 0, stream>>>(af, cf, dout + (size_t)BB * TT * VV);
}